// Round 6
// baseline (752.375 us; speedup 1.0000x reference)
//
#include <hip/hip_runtime.h>

#define DEVINL __device__ __forceinline__

typedef __attribute__((ext_vector_type(8))) short bf16x8;
typedef __attribute__((ext_vector_type(4))) short bf16x4;
typedef __attribute__((ext_vector_type(4))) float f32x4;
typedef __attribute__((ext_vector_type(2))) unsigned int u32x2;

static constexpr int S = 4096;
static constexpr int D = 768;
static constexpr float POST_SCALE = 19.595917942265423f; // sqrt(384)

#define MFMA16(a, b, c) __builtin_amdgcn_mfma_f32_16x16x32_bf16((a), (b), (c), 0, 0, 0)

// K=16 bf16 MFMA: A/B = 4 bf16 (2 VGPR). Prefer builtin; fall back to asm.
#if __has_builtin(__builtin_amdgcn_mfma_f32_16x16x16bf16_1k)
DEVINL f32x4 pv_mfma(bf16x4 a, bf16x4 b, f32x4 c) {
  return __builtin_amdgcn_mfma_f32_16x16x16bf16_1k(a, b, c, 0, 0, 0);
}
#else
DEVINL f32x4 pv_mfma(bf16x4 a, bf16x4 b, f32x4 c) {
  asm("v_mfma_f32_16x16x16_bf16 %0, %1, %2, %0" : "+v"(c) : "v"(a), "v"(b));
  return c;
}
#endif

DEVINL unsigned short f2bf(float f) {
  union { float f; unsigned u; } v; v.f = f;
  unsigned r = (v.u + 0x7FFFu + ((v.u >> 16) & 1u)) >> 16;  // RNE
  return (unsigned short)r;
}

// ---------------- fp32 -> bf16 convert ----------------
__global__ void cvt_kernel(const float* __restrict__ src,
                           unsigned short* __restrict__ dst, int n4) {
  int i = blockIdx.x * blockDim.x + threadIdx.x;
  if (i >= n4) return;
  float4 v = reinterpret_cast<const float4*>(src)[i];
  ushort4 o;
  o.x = f2bf(v.x); o.y = f2bf(v.y); o.z = f2bf(v.z); o.w = f2bf(v.w);
  reinterpret_cast<ushort4*>(dst)[i] = o;
}

// ---------------- (a+b+c+d) fp32 -> bf16 ----------------
__global__ void addcvt4_kernel(const float* __restrict__ a,
                               const float* __restrict__ b,
                               const float* __restrict__ c,
                               const float* __restrict__ d,
                               unsigned short* __restrict__ dst, int n4) {
  int i = blockIdx.x * blockDim.x + threadIdx.x;
  if (i >= n4) return;
  float4 va = reinterpret_cast<const float4*>(a)[i];
  float4 vb = reinterpret_cast<const float4*>(b)[i];
  float4 vc = reinterpret_cast<const float4*>(c)[i];
  float4 vd = reinterpret_cast<const float4*>(d)[i];
  ushort4 o;
  o.x = f2bf(va.x + vb.x + vc.x + vd.x);
  o.y = f2bf(va.y + vb.y + vc.y + vd.y);
  o.z = f2bf(va.z + vb.z + vc.z + vd.z);
  o.w = f2bf(va.w + vb.w + vc.w + vd.w);
  reinterpret_cast<ushort4*>(dst)[i] = o;
}

// ---------------- bf16 transpose [S,D] -> [D,S] ----------------
__global__ void transpose_kernel(const unsigned short* __restrict__ in,
                                 unsigned short* __restrict__ out) {
  __shared__ unsigned short tile[32][33];
  int d0 = blockIdx.x * 32, t0 = blockIdx.y * 32;
  int tx = threadIdx.x, ty = threadIdx.y;  // block (32,8)
#pragma unroll
  for (int j = 0; j < 4; j++)
    tile[ty + j * 8][tx] = in[(size_t)(t0 + ty + j * 8) * D + d0 + tx];
  __syncthreads();
#pragma unroll
  for (int j = 0; j < 4; j++)
    out[(size_t)(d0 + ty + j * 8) * S + t0 + tx] = tile[tx][ty + j * 8];
}

// ---------------- GEMM: C[M,N] = A[M,K] @ B[N,K]^T + bias ----------------
template <bool F32OUT>
__global__ __launch_bounds__(256) void gemm_bt(
    const unsigned short* __restrict__ A, const unsigned short* __restrict__ B,
    const float* __restrict__ bias, void* __restrict__ Cout,
    int M, int N, int K) {
  int w = threadIdx.x >> 6, lane = threadIdx.x & 63;
  int r = lane & 15, b = lane >> 4;
  int rowbase = blockIdx.y * 128 + (w >> 1) * 64;
  int colbase = blockIdx.x * 128 + (w & 1) * 64;
  f32x4 acc[4][4] = {};
  for (int kk = 0; kk < K; kk += 32) {
    bf16x8 af[4], bfr[4];
#pragma unroll
    for (int m = 0; m < 4; m++)
      af[m] = *reinterpret_cast<const bf16x8*>(A + (size_t)(rowbase + m * 16 + r) * K + kk + b * 8);
#pragma unroll
    for (int n = 0; n < 4; n++)
      bfr[n] = *reinterpret_cast<const bf16x8*>(B + (size_t)(colbase + n * 16 + r) * K + kk + b * 8);
#pragma unroll
    for (int m = 0; m < 4; m++)
#pragma unroll
      for (int n = 0; n < 4; n++)
        acc[m][n] = MFMA16(af[m], bfr[n], acc[m][n]);
  }
#pragma unroll
  for (int m = 0; m < 4; m++)
#pragma unroll
    for (int n = 0; n < 4; n++)
#pragma unroll
      for (int i = 0; i < 4; i++) {
        int row = rowbase + m * 16 + b * 4 + i;
        int col = colbase + n * 16 + r;
        float v = acc[m][n][i] + bias[col];
        if (F32OUT)
          reinterpret_cast<float*>(Cout)[(size_t)row * N + col] = v;
        else
          reinterpret_cast<unsigned short*>(Cout)[(size_t)row * N + col] = f2bf(v);
      }
}

// ---------------- fused attention v4: barrier-free, LDS-free ----------------
// Wave = 16 s-rows x ALL 12 heads x a 1024-t slice; chunk = 16 t.
// score: C[t][s] = mfma_16x16x32(A=Q, B=K): lane holds s=r (col), t=4b+i (rows)
//   -> 12-head softmax is lane-local (4 t-points per lane), no max-sub needed
//      (|score| < ~18, exp safe in f32).
// P pack: cvt_pk to bf16 -> lane's 4 t-values == EXACTLY the A-fragment of
//   mfma_16x16x16_bf16 (k = (lane>>4)*4+j). PV needs no cross-lane exchange.
// PV: O[s][d] += P @ V, B-frag = Vt[h*64+dt*16+r][t0+4b..+3] (8B loads).
// K-fragments resident in 96 VGPRs; Q reloaded for next chunk under softmax;
// V issued in two halves under softmax / early PV. Zero LDS, zero barriers.
__global__ __launch_bounds__(256, 1) void attn_kernel(
    const unsigned short* __restrict__ Qb, const unsigned short* __restrict__ Kb,
    const unsigned short* __restrict__ Vt, float* __restrict__ Opart) {
  // decode: group blocks of the same t-slice onto the same XCD (n%8 heuristic)
  const int n = blockIdx.x;            // 0..255
  const int xcd = n & 7, slot = n >> 3;
  const int by = xcd >> 1;             // t-slice 0..3
  const int bx = (xcd & 1) * 32 + slot;// s-block 0..63
  const int w = threadIdx.x >> 6, lane = threadIdx.x & 63;
  const int r = lane & 15, b = lane >> 4;
  const int tbeg = by * 1024;
  const int srow = bx * 64 + w * 16 + r;

  // ---- K fragments: resident for whole kernel (12h x 2 = 96 VGPR) ----
  bf16x8 kf[12][2];
  {
    const unsigned short* kp = Kb + (size_t)srow * D + b * 8;
#pragma unroll
    for (int h = 0; h < 12; h++) {
      kf[h][0] = *reinterpret_cast<const bf16x8*>(kp + h * 64);
      kf[h][1] = *reinterpret_cast<const bf16x8*>(kp + h * 64 + 32);
    }
  }

  f32x4 oacc[12][4] = {};  // 192 acc regs

  // ---- Q for chunk 0 ----
  const unsigned short* qbase = Qb + (size_t)(tbeg + r) * D + b * 8;
  bf16x8 qcur[12][2];
#pragma unroll
  for (int h = 0; h < 12; h++) {
    qcur[h][0] = *reinterpret_cast<const bf16x8*>(qbase + h * 64);
    qcur[h][1] = *reinterpret_cast<const bf16x8*>(qbase + h * 64 + 32);
  }

  const unsigned short* vrow = Vt + (size_t)r * S + 4 * b;  // + (h*64+dt*16)*S + tc

  for (int c = 0; c < 64; c++) {
    const int tc = tbeg + c * 16;

    // ---- score: 12 heads, pure-register MFMA ----
    f32x4 acc[12];
#pragma unroll
    for (int h = 0; h < 12; h++) {
      f32x4 t = {};
      t = MFMA16(qcur[h][0], kf[h][0], t);
      t = MFMA16(qcur[h][1], kf[h][1], t);
      acc[h] = t;
    }

    // ---- reload Q for next chunk (latency hidden by softmax+PV) ----
    {
      const int cn = (c < 63) ? c + 1 : c;
      const unsigned short* qn = qbase + (size_t)cn * 16 * D;
#pragma unroll
      for (int h = 0; h < 12; h++) {
        qcur[h][0] = *reinterpret_cast<const bf16x8*>(qn + h * 64);
        qcur[h][1] = *reinterpret_cast<const bf16x8*>(qn + h * 64 + 32);
      }
    }

    // ---- issue V half A (h=0..5) ----
    bf16x4 vfa[6][4];
#pragma unroll
    for (int h = 0; h < 6; h++)
#pragma unroll
      for (int dt = 0; dt < 4; dt++)
        vfa[h][dt] = *reinterpret_cast<const bf16x4*>(
            vrow + (size_t)(h * 64 + dt * 16) * S + tc);

    // ---- softmax over heads (no max-sub; scores bounded ~|18|) ----
    float s0f = 0.f, s1f = 0.f, s2f = 0.f, s3f = 0.f;
#pragma unroll
    for (int h = 0; h < 12; h++) {
      acc[h][0] = __expf(acc[h][0]); s0f += acc[h][0];
      acc[h][1] = __expf(acc[h][1]); s1f += acc[h][1];
      acc[h][2] = __expf(acc[h][2]); s2f += acc[h][2];
      acc[h][3] = __expf(acc[h][3]); s3f += acc[h][3];
    }
    s0f = POST_SCALE * __builtin_amdgcn_rcpf(s0f);
    s1f = POST_SCALE * __builtin_amdgcn_rcpf(s1f);
    s2f = POST_SCALE * __builtin_amdgcn_rcpf(s2f);
    s3f = POST_SCALE * __builtin_amdgcn_rcpf(s3f);

    // ---- pack P: lane's 4 t-values -> K=16 A-fragment directly ----
    bf16x4 pf[12];
#pragma unroll
    for (int h = 0; h < 12; h++) {
      u32x2 pk;
      float p0 = acc[h][0] * s0f, p1 = acc[h][1] * s1f;
      float p2 = acc[h][2] * s2f, p3 = acc[h][3] * s3f;
      asm("v_cvt_pk_bf16_f32 %0, %1, %2" : "=v"(pk.x) : "v"(p0), "v"(p1));
      asm("v_cvt_pk_bf16_f32 %0, %1, %2" : "=v"(pk.y) : "v"(p2), "v"(p3));
      pf[h] = __builtin_bit_cast(bf16x4, pk);
    }

    // ---- issue V half B (h=6..11) ----
    bf16x4 vfb[6][4];
#pragma unroll
    for (int h = 0; h < 6; h++)
#pragma unroll
      for (int dt = 0; dt < 4; dt++)
        vfb[h][dt] = *reinterpret_cast<const bf16x4*>(
            vrow + (size_t)((h + 6) * 64 + dt * 16) * S + tc);

    // ---- PV: 48 K=16 MFMAs, all register-resident ----
#pragma unroll
    for (int h = 0; h < 6; h++)
#pragma unroll
      for (int dt = 0; dt < 4; dt++)
        oacc[h][dt] = pv_mfma(pf[h], vfa[h][dt], oacc[h][dt]);
#pragma unroll
    for (int h = 0; h < 6; h++)
#pragma unroll
      for (int dt = 0; dt < 4; dt++)
        oacc[h + 6][dt] = pv_mfma(pf[h + 6], vfb[h][dt], oacc[h + 6][dt]);
  }

  // ---- O writeback: row s = srow-base + 4b+i, col d = h*64+dt*16+r ----
  float* Op = Opart + (size_t)by * S * D;
  const int sbase = bx * 64 + w * 16;
#pragma unroll
  for (int h = 0; h < 12; h++)
#pragma unroll
    for (int dt = 0; dt < 4; dt++)
#pragma unroll
      for (int i = 0; i < 4; i++) {
        int row = sbase + b * 4 + i;
        int col = h * 64 + dt * 16 + r;
        Op[(size_t)row * D + col] = oacc[h][dt][i];
      }
}

extern "C" void kernel_launch(void* const* d_in, const int* in_sizes, int n_in,
                              void* d_out, int out_size, void* d_ws, size_t ws_size,
                              hipStream_t stream) {
  const float* x  = (const float*)d_in[0];
  const float* Wq = (const float*)d_in[1];
  const float* bq = (const float*)d_in[2];
  const float* Wk = (const float*)d_in[3];
  const float* bk = (const float*)d_in[4];
  const float* Wv = (const float*)d_in[5];
  const float* bv = (const float*)d_in[6];
  const float* Wo = (const float*)d_in[7];
  const float* bo = (const float*)d_in[8];
  float* out = (float*)d_out;

  char* ws = (char*)d_ws;
  size_t off = 0;
  auto walloc = [&](size_t bytes) -> void* {
    void* p = ws + off;
    off += (bytes + 255) & ~(size_t)255;
    return p;
  };
  unsigned short* xb  = (unsigned short*)walloc((size_t)S * D * 2);
  unsigned short* Wqb = (unsigned short*)walloc((size_t)D * D * 2);
  unsigned short* Wkb = (unsigned short*)walloc((size_t)D * D * 2);
  unsigned short* Wvb = (unsigned short*)walloc((size_t)D * D * 2);
  unsigned short* Wob = (unsigned short*)walloc((size_t)D * D * 2);
  unsigned short* Qb  = (unsigned short*)walloc((size_t)S * D * 2);
  unsigned short* Kb  = (unsigned short*)walloc((size_t)S * D * 2);
  unsigned short* Vb  = (unsigned short*)walloc((size_t)S * D * 2);
  unsigned short* Vt  = (unsigned short*)walloc((size_t)S * D * 2);
  unsigned short* Ob  = (unsigned short*)walloc((size_t)S * D * 2);
  float* Opart = (float*)walloc((size_t)4 * S * D * 4);

  int n4;
  n4 = S * D / 4;
  cvt_kernel<<<(n4 + 255) / 256, 256, 0, stream>>>(x, xb, n4);
  n4 = D * D / 4;
  cvt_kernel<<<(n4 + 255) / 256, 256, 0, stream>>>(Wq, Wqb, n4);
  cvt_kernel<<<(n4 + 255) / 256, 256, 0, stream>>>(Wk, Wkb, n4);
  cvt_kernel<<<(n4 + 255) / 256, 256, 0, stream>>>(Wv, Wvb, n4);
  cvt_kernel<<<(n4 + 255) / 256, 256, 0, stream>>>(Wo, Wob, n4);

  dim3 gg(D / 128, S / 128);  // (6, 32)
  gemm_bt<false><<<gg, 256, 0, stream>>>(xb, Wqb, bq, Qb, S, D, D);
  gemm_bt<false><<<gg, 256, 0, stream>>>(xb, Wkb, bk, Kb, S, D, D);
  gemm_bt<false><<<gg, 256, 0, stream>>>(xb, Wvb, bv, Vb, S, D, D);

  transpose_kernel<<<dim3(D / 32, S / 32), dim3(32, 8), 0, stream>>>(Vb, Vt);

  attn_kernel<<<256, 256, 0, stream>>>(Qb, Kb, Vt, Opart);

  n4 = S * D / 4;
  addcvt4_kernel<<<(n4 + 255) / 256, 256, 0, stream>>>(
      Opart, Opart + (size_t)S * D, Opart + (size_t)2 * S * D,
      Opart + (size_t)3 * S * D, Ob, n4);

  gemm_bt<true><<<gg, 256, 0, stream>>>(Ob, Wob, bo, out, S, D, D);
}